// Round 2
// baseline (207.525 us; speedup 1.0000x reference)
//
#include <hip/hip_runtime.h>
#include <hip/hip_bf16.h>

typedef __attribute__((ext_vector_type(8))) short short8;      // 8 bf16 (4 VGPRs) MFMA A/B frag
typedef __attribute__((ext_vector_type(4))) float floatx4;     // MFMA C/D frag
typedef __attribute__((ext_vector_type(4))) unsigned short ushort4b; // 8B LDS store

#define BTOT 65536

__device__ __forceinline__ unsigned short f2bf(float f) {
  unsigned u = __float_as_uint(f);
  unsigned r = u + 0x7FFFu + ((u >> 16) & 1u);   // RNE
  return (unsigned short)(r >> 16);
}
__device__ __forceinline__ float bf2f(unsigned short u) {
  return __uint_as_float(((unsigned)u) << 16);
}

// ---------------------------------------------------------------------------
// K1: h1 = relu(x @ W1^T + b1)   x:[B,1024] f32, W1:[120,1024], h1:[B,120] f32
// 128x128 tile (N padded 120->128), BK=64, bf16 MFMA 16x16x32.
// 512 threads = 8 waves as 4(m) x 2(n); each wave 32 rows x 64 cols.
// LDS rows are 128B -> XOR-swizzle ((row&7)<<4) to kill the 16-way conflict.
// ---------------------------------------------------------------------------
__global__ __launch_bounds__(512) void k1_gemm1(
    const float* __restrict__ x, const float* __restrict__ w1,
    const float* __restrict__ b1, float* __restrict__ h1) {
  __shared__ unsigned char lds[(128 * 64 + 128 * 64) * 2];  // 32 KB
  unsigned char* Xs = lds;                // [128][64] bf16 swizzled
  unsigned char* Ws = lds + 128 * 64 * 2; // [128][64] bf16 swizzled

  const int tid = threadIdx.x;
  const int lane = tid & 63;
  const int wid = tid >> 6;
  const int wm = wid >> 1;   // 0..3
  const int wn = wid & 1;    // 0..1
  const int l15 = lane & 15;
  const int l4 = lane >> 4;
  const long row0 = (long)blockIdx.x * 128;

  floatx4 acc[2][4];
#pragma unroll
  for (int i = 0; i < 2; ++i)
#pragma unroll
    for (int j = 0; j < 4; ++j)
      acc[i][j] = floatx4{0.f, 0.f, 0.f, 0.f};

  for (int k0 = 0; k0 < 1024; k0 += 64) {
    __syncthreads();
#pragma unroll
    for (int i = 0; i < 4; ++i) {
      int idx = tid + i * 512;          // 2048 = 128 rows x 16 float4
      int r = idx >> 4, c4 = idx & 15;
      float4 v = *(const float4*)(x + (row0 + r) * 1024 + k0 + c4 * 4);
      ushort4b u;
      u.x = f2bf(v.x); u.y = f2bf(v.y); u.z = f2bf(v.z); u.w = f2bf(v.w);
      *(ushort4b*)(Xs + r * 128 + ((c4 * 8) ^ ((r & 7) << 4))) = u;
      ushort4b uw;
      if (r < 120) {
        float4 wv = *(const float4*)(w1 + (long)r * 1024 + k0 + c4 * 4);
        uw.x = f2bf(wv.x); uw.y = f2bf(wv.y); uw.z = f2bf(wv.z); uw.w = f2bf(wv.w);
      } else {
        uw.x = 0; uw.y = 0; uw.z = 0; uw.w = 0;
      }
      *(ushort4b*)(Ws + r * 128 + ((c4 * 8) ^ ((r & 7) << 4))) = uw;
    }
    __syncthreads();
#pragma unroll
    for (int ss = 0; ss < 2; ++ss) {   // two K=32 sub-steps
      short8 a[2], b[4];
#pragma unroll
      for (int mt = 0; mt < 2; ++mt) {
        int r = wm * 32 + mt * 16 + l15;
        a[mt] = *(const short8*)(Xs + r * 128 + ((ss * 64 + l4 * 16) ^ ((r & 7) << 4)));
      }
#pragma unroll
      for (int nt = 0; nt < 4; ++nt) {
        int n = wn * 64 + nt * 16 + l15;
        b[nt] = *(const short8*)(Ws + n * 128 + ((ss * 64 + l4 * 16) ^ ((n & 7) << 4)));
      }
#pragma unroll
      for (int mt = 0; mt < 2; ++mt)
#pragma unroll
        for (int nt = 0; nt < 4; ++nt)
          acc[mt][nt] = __builtin_amdgcn_mfma_f32_16x16x32_bf16(a[mt], b[nt], acc[mt][nt], 0, 0, 0);
    }
  }
  // epilogue: C/D layout col=lane&15, row=(lane>>4)*4+reg  [learn_hip m89]
#pragma unroll
  for (int nt = 0; nt < 4; ++nt) {
    int col = wn * 64 + nt * 16 + l15;
    if (col < 120) {
      float bias = b1[col];
#pragma unroll
      for (int mt = 0; mt < 2; ++mt) {
#pragma unroll
        for (int r = 0; r < 4; ++r) {
          long row = row0 + wm * 32 + mt * 16 + l4 * 4 + r;
          float v = acc[mt][nt][r] + bias;
          h1[row * 120 + col] = v > 0.f ? v : 0.f;
        }
      }
    }
  }
}

// ---------------------------------------------------------------------------
// K2: fused  h2 = relu(h1 @ W2^T + b2) -> LayerNorm -> 10 dots vs sms ->
//            logits_common + logits_spec -> weighted-CE partial sums.
// One block = 64 rows, 512 threads = 8 waves; wave w owns n-slice [w*64,+64).
// LDS carve (dynamic 147456B):
//   [0,131072)       W2s [512][128] bf16 swz   --(after GEMM)--> h2s [64][512] f32
//   [131072,147456)  h1s [64][128] bf16 swz    --(after GEMM)--> smss [5][512] bf16-pairs
//                                              + wp[8][4] at +10240
// ---------------------------------------------------------------------------
__global__ __launch_bounds__(512) void k2_fused(
    const float* __restrict__ h1g, const float* __restrict__ w2,
    const float* __restrict__ b2, const float* __restrict__ ln_g,
    const float* __restrict__ ln_b, const float* __restrict__ sms,
    const float* __restrict__ sm_biases, const float* __restrict__ embs,
    const float* __restrict__ cs_wt, const int* __restrict__ labels,
    const int* __restrict__ domain, float* __restrict__ out,
    float* __restrict__ partials) {
  extern __shared__ unsigned char lds[];
  unsigned char* W2s = lds;                     // [512][128] bf16 swz
  unsigned char* h1s = lds + 131072;            // [64][128] bf16 swz
  float* h2sf = (float*)lds;                    // [64][512] f32 (aliases W2s)
  unsigned* smss2 = (unsigned*)(lds + 131072);  // [5][512] bf16-pair (aliases h1s)
  float* wp = (float*)(lds + 131072 + 10240);   // [8][4]

  const int tid = threadIdx.x;
  const int lane = tid & 63;
  const int wid = tid >> 6;     // 0..7
  const int l15 = lane & 15, l4 = lane >> 4;
  const long row0 = (long)blockIdx.x * 64;

  // ---- stage W2 rows (one row per thread), pad k 120..127 with zeros
  {
    int n = tid;
#pragma unroll
    for (int c4 = 0; c4 < 30; ++c4) {
      float4 v = *(const float4*)(w2 + (long)n * 120 + c4 * 4);
      ushort4b u;
      u.x = f2bf(v.x); u.y = f2bf(v.y); u.z = f2bf(v.z); u.w = f2bf(v.w);
      *(ushort4b*)(W2s + n * 256 + ((c4 * 8) ^ ((n & 7) << 4))) = u;
    }
    ushort4b z; z.x = 0; z.y = 0; z.z = 0; z.w = 0;
    *(ushort4b*)(W2s + n * 256 + ((240) ^ ((n & 7) << 4))) = z;
    *(ushort4b*)(W2s + n * 256 + ((248) ^ ((n & 7) << 4))) = z;
  }
  // ---- stage h1 tile [64][120->128]
  for (int i = tid; i < 64 * 30; i += 512) {
    int r = i / 30, c4 = i % 30;
    float4 v = *(const float4*)(h1g + (row0 + r) * 120 + c4 * 4);
    ushort4b u;
    u.x = f2bf(v.x); u.y = f2bf(v.y); u.z = f2bf(v.z); u.w = f2bf(v.w);
    *(ushort4b*)(h1s + r * 256 + ((c4 * 8) ^ ((r & 7) << 4))) = u;
  }
  if (tid < 128) {
    int r = tid >> 1, c4 = 30 + (tid & 1);
    ushort4b z; z.x = 0; z.y = 0; z.z = 0; z.w = 0;
    *(ushort4b*)(h1s + r * 256 + ((c4 * 8) ^ ((r & 7) << 4))) = z;
  }
  __syncthreads();

  // ---- GEMM2: 64x64 per wave, K=128
  floatx4 acc[4][4];
#pragma unroll
  for (int i = 0; i < 4; ++i)
#pragma unroll
    for (int j = 0; j < 4; ++j)
      acc[i][j] = floatx4{0.f, 0.f, 0.f, 0.f};
  const int n0 = wid * 64;
#pragma unroll
  for (int ks = 0; ks < 4; ++ks) {
    short8 a[4], b[4];
#pragma unroll
    for (int mt = 0; mt < 4; ++mt) {
      int r = mt * 16 + l15;
      a[mt] = *(const short8*)(h1s + r * 256 + ((ks * 64 + l4 * 16) ^ ((r & 7) << 4)));
    }
#pragma unroll
    for (int nt = 0; nt < 4; ++nt) {
      int n = n0 + nt * 16 + l15;
      b[nt] = *(const short8*)(W2s + n * 256 + ((ks * 64 + l4 * 16) ^ ((n & 7) << 4)));
    }
#pragma unroll
    for (int mt = 0; mt < 4; ++mt)
#pragma unroll
      for (int nt = 0; nt < 4; ++nt)
        acc[mt][nt] = __builtin_amdgcn_mfma_f32_16x16x32_bf16(a[mt], b[nt], acc[mt][nt], 0, 0, 0);
  }
  __syncthreads();   // all frag reads done; safe to overwrite W2s/h1s

  // ---- h2 = relu(acc + b2) into LDS [64][512] f32
#pragma unroll
  for (int nt = 0; nt < 4; ++nt) {
    int col = n0 + nt * 16 + l15;
    float bias = b2[col];
#pragma unroll
    for (int mt = 0; mt < 4; ++mt)
#pragma unroll
      for (int r = 0; r < 4; ++r) {
        int rowl = mt * 16 + l4 * 4 + r;
        float v = acc[mt][nt][r] + bias;
        h2sf[rowl * 512 + col] = v > 0.f ? v : 0.f;
      }
  }
  // ---- stage sms as packed bf16 pairs (c=0,1)
  for (int i = tid; i < 5 * 512; i += 512) {
    int kk = i >> 9, hh = i & 511;
    float s0 = sms[kk * 1024 + hh * 2 + 0];
    float s1 = sms[kk * 1024 + hh * 2 + 1];
    smss2[i] = (unsigned)f2bf(s0) | ((unsigned)f2bf(s1) << 16);
  }
  __syncthreads();

  // ---- hoisted per-thread constants (col = lane + 64j fixed across rows)
  float g8[8], bb8[8];
  unsigned su[5][8];
#pragma unroll
  for (int j = 0; j < 8; ++j) {
    int col = lane + 64 * j;
    g8[j] = ln_g[col];
    bb8[j] = ln_b[col];
#pragma unroll
    for (int kk = 0; kk < 5; ++kk) su[kk][j] = smss2[kk * 512 + col];
  }
  float sb[5][2];
#pragma unroll
  for (int kk = 0; kk < 5; ++kk) {
    sb[kk][0] = sm_biases[kk * 2];
    sb[kk][1] = sm_biases[kk * 2 + 1];
  }
  const float cw0 = tanhf(cs_wt[0]);

  float wsum = 0.f, scom = 0.f, sspec = 0.f;
  for (int rr = 0; rr < 8; ++rr) {
    int rowl = wid * 8 + rr;
    float v[8];
    float s = 0.f, ss2 = 0.f;
#pragma unroll
    for (int j = 0; j < 8; ++j) {
      v[j] = h2sf[rowl * 512 + lane + 64 * j];
      s += v[j];
      ss2 += v[j] * v[j];
    }
#pragma unroll
    for (int o = 32; o >= 1; o >>= 1) {
      s += __shfl_xor(s, o);
      ss2 += __shfl_xor(ss2, o);
    }
    float mu = s * (1.f / 512.f);
    float var = ss2 * (1.f / 512.f) - mu * mu;
    float rs = rsqrtf(var + 1e-5f);
    float pd[10];
#pragma unroll
    for (int q = 0; q < 10; ++q) pd[q] = 0.f;
#pragma unroll
    for (int j = 0; j < 8; ++j) {
      float hn = (v[j] - mu) * rs * g8[j] + bb8[j];
#pragma unroll
      for (int kk = 0; kk < 5; ++kk) {
        unsigned p = su[kk][j];
        pd[kk * 2]     += hn * bf2f((unsigned short)(p & 0xFFFFu));
        pd[kk * 2 + 1] += hn * bf2f((unsigned short)(p >> 16));
      }
    }
#pragma unroll
    for (int o = 32; o >= 1; o >>= 1)
#pragma unroll
      for (int q = 0; q < 10; ++q) pd[q] += __shfl_xor(pd[q], o);

    long grow = row0 + rowl;
    int lab = labels[grow];
    int dm = domain[grow];
    float cw[5];
    cw[0] = cw0;
#pragma unroll
    for (int kk = 1; kk < 5; ++kk) cw[kk] = tanhf(embs[dm * 4 + kk - 1]);
    float lc0 = pd[0] + sb[0][0], lc1 = pd[1] + sb[0][1];
    float ls0 = 0.f, ls1 = 0.f;
#pragma unroll
    for (int kk = 0; kk < 5; ++kk) {
      ls0 += cw[kk] * (pd[kk * 2] + sb[kk][0]);
      ls1 += cw[kk] * (pd[kk * 2 + 1] + sb[kk][1]);
    }
    float m1 = fmaxf(lc0, lc1);
    float lse1 = m1 + logf(expf(lc0 - m1) + expf(lc1 - m1));
    float nllc = lse1 - (lab ? lc1 : lc0);
    float m2 = fmaxf(ls0, ls1);
    float lse2 = m2 + logf(expf(ls0 - m2) + expf(ls1 - m2));
    float nlls = lse2 - (lab ? ls1 : ls0);
    float wl = lab ? 0.9f : 0.1f;   // CE_W = [0.1, 0.9]
    wsum += wl;
    scom += wl * nllc;
    sspec += wl * nlls;
    if (lane == 0) {
      out[1 + grow * 2 + 0] = lc0;
      out[1 + grow * 2 + 1] = lc1;
    }
  }
  if (lane == 0) {
    wp[wid * 4] = wsum;
    wp[wid * 4 + 1] = scom;
    wp[wid * 4 + 2] = sspec;
  }
  __syncthreads();
  if (tid == 0) {
    float a = 0.f, b = 0.f, c = 0.f;
    for (int w = 0; w < 8; ++w) {
      a += wp[w * 4]; b += wp[w * 4 + 1]; c += wp[w * 4 + 2];
    }
    partials[(long)blockIdx.x * 4]     = a;
    partials[(long)blockIdx.x * 4 + 1] = b;
    partials[(long)blockIdx.x * 4 + 2] = c;
  }
}

// ---------------------------------------------------------------------------
// K3: deterministic final reduce + orth loss (exact f32) + scalars.
// out layout: [0]=loss, [1..131072]=logits_common, [131073]=class,
//             [131074]=spec, [131075]=orth
// ---------------------------------------------------------------------------
__global__ __launch_bounds__(256) void k3_finalize(
    const float* __restrict__ partials, const float* __restrict__ sms,
    float* __restrict__ out) {
  __shared__ float wsums[4][3];
  __shared__ float ow[4];
  const int tid = threadIdx.x;
  const int lane = tid & 63, wid = tid >> 6;
  float sw = 0.f, sc = 0.f, ss = 0.f;
  for (int i = tid; i < 1024; i += 256) {
    sw += partials[i * 4];
    sc += partials[i * 4 + 1];
    ss += partials[i * 4 + 2];
  }
#pragma unroll
  for (int o = 32; o >= 1; o >>= 1) {
    sw += __shfl_xor(sw, o);
    sc += __shfl_xor(sc, o);
    ss += __shfl_xor(ss, o);
  }
  if (lane == 0) { wsums[wid][0] = sw; wsums[wid][1] = sc; wsums[wid][2] = ss; }

  // orth: cps[c][k][j] = sum_h sms[k,h,c]*sms[j,h,c]; mean((cps - I)^2) over 50
  float osum = 0.f;
  for (int p = wid; p < 50; p += 4) {
    int c = p / 25, kk = (p / 5) % 5, j = p % 5;
    float acc = 0.f;
#pragma unroll
    for (int hh = 0; hh < 8; ++hh) {
      int h = lane + 64 * hh;
      acc += sms[kk * 1024 + h * 2 + c] * sms[j * 1024 + h * 2 + c];
    }
#pragma unroll
    for (int o = 32; o >= 1; o >>= 1) acc += __shfl_xor(acc, o);
    float d = acc - ((kk == j) ? 1.f : 0.f);
    osum += d * d;
  }
  if (lane == 0) ow[wid] = osum;
  __syncthreads();
  if (tid == 0) {
    float SW = 0.f, SC = 0.f, SS = 0.f, OS = 0.f;
    for (int w = 0; w < 4; ++w) {
      SW += wsums[w][0]; SC += wsums[w][1]; SS += wsums[w][2]; OS += ow[w];
    }
    float orth = OS * (1.f / 50.f);
    float cls = SC / SW;
    float spec = SS / SW;
    out[0] = cls + spec + orth;
    out[131073] = cls;
    out[131074] = spec;
    out[131075] = orth;
  }
}

extern "C" void kernel_launch(void* const* d_in, const int* in_sizes, int n_in,
                              void* d_out, int out_size, void* d_ws, size_t ws_size,
                              hipStream_t stream) {
  const float* x      = (const float*)d_in[0];
  const int* labels   = (const int*)d_in[1];
  const int* domain   = (const int*)d_in[2];
  const float* fc1_w  = (const float*)d_in[3];
  const float* fc1_b  = (const float*)d_in[4];
  const float* fc2_w  = (const float*)d_in[5];
  const float* fc2_b  = (const float*)d_in[6];
  const float* ln_g   = (const float*)d_in[7];
  const float* ln_b   = (const float*)d_in[8];
  const float* sms    = (const float*)d_in[9];
  const float* sm_b   = (const float*)d_in[10];
  const float* embs   = (const float*)d_in[11];
  const float* cs_wt  = (const float*)d_in[12];
  float* out = (float*)d_out;
  float* h1 = (float*)d_ws;                                   // B*120 f32 = 31.46 MB
  float* partials = (float*)((char*)d_ws + (size_t)BTOT * 120 * 4); // 1024*4 f32

  // opt-in for 144KB dynamic LDS (host-side attr, capture-safe, idempotent)
  (void)hipFuncSetAttribute((const void*)k2_fused,
                            hipFuncAttributeMaxDynamicSharedMemorySize, 147456);

  hipLaunchKernelGGL(k1_gemm1, dim3(BTOT / 128), dim3(512), 0, stream,
                     x, fc1_w, fc1_b, h1);
  hipLaunchKernelGGL(k2_fused, dim3(BTOT / 64), dim3(512), 147456, stream,
                     h1, fc2_w, fc2_b, ln_g, ln_b, sms, sm_b, embs, cs_wt,
                     labels, domain, out, partials);
  hipLaunchKernelGGL(k3_finalize, dim3(1), dim3(256), 0, stream,
                     partials, sms, out);
}

// Round 3
// 113.368 us; speedup vs baseline: 1.8305x; 1.8305x over previous
//
#include <hip/hip_runtime.h>
#include <hip/hip_bf16.h>

typedef __attribute__((ext_vector_type(8))) short short8;        // 8 bf16 MFMA A/B frag
typedef __attribute__((ext_vector_type(4))) float floatx4;       // MFMA C/D frag
typedef __attribute__((ext_vector_type(8))) unsigned short ushort8;

#define BTOT 65536
// ws byte offsets
#define WS_W1BF   0u          // 256 KB: [16 ks][16384B] pre-swizzled LDS image of W1 bf16
#define WS_W2BF   262144u     // 128 KB: pre-swizzled [512][128] bf16 image
#define WS_GBF    393216u     // 16 KB: B-frag image of G[q][k] = ln_g*sms
#define WS_CONST  409600u     // 64 f32: [0..9]=Cb', [16]=tanh(cs), [32..59]=tanh(embs)
#define WS_H1BF   524288u     // 16 MB: 1024 blocks x 16384B pre-swizzled h1 bf16
#define WS_PART   17301504u   // 1024 x 4 f32 partials

__device__ __forceinline__ unsigned short f2bf(float f) {
  unsigned u = __float_as_uint(f);
  unsigned r = u + 0x7FFFu + ((u >> 16) & 1u);   // RNE
  return (unsigned short)(r >> 16);
}

__device__ __forceinline__ void gload16(const void* g, void* l) {
  __builtin_amdgcn_global_load_lds(
      (const __attribute__((address_space(1))) unsigned int*)g,
      (__attribute__((address_space(3))) unsigned int*)l, 16, 0, 0);
}

// ---------------------------------------------------------------------------
// K0: one-shot prep. Pre-convert weights to bf16 pre-swizzled LDS images,
// build G = g (.) sms frag image, constants Cb' and tanh tables.
// ---------------------------------------------------------------------------
__global__ __launch_bounds__(256) void k0_prep(
    const float* __restrict__ w1, const float* __restrict__ w2,
    const float* __restrict__ ln_g, const float* __restrict__ ln_b,
    const float* __restrict__ sms, const float* __restrict__ smb,
    const float* __restrict__ embs, const float* __restrict__ cs,
    unsigned char* __restrict__ ws) {
  const int blk = blockIdx.x, tid = threadIdx.x;
  if (blk < 32) {               // W1 image: [ks][n 0..127][chunk c'], c = c'^(n&7)
    for (int g = blk * 256 + tid; g < 16384; g += 32 * 256) {
      int ks = g >> 10, d = g & 1023;
      int n = d >> 3, cp = d & 7, c = cp ^ (n & 7);
      ushort8 u;
      if (n < 120) {
        const float* s = w1 + n * 1024 + ks * 64 + c * 8;
        float4 v0 = *(const float4*)s, v1 = *(const float4*)(s + 4);
        u[0] = f2bf(v0.x); u[1] = f2bf(v0.y); u[2] = f2bf(v0.z); u[3] = f2bf(v0.w);
        u[4] = f2bf(v1.x); u[5] = f2bf(v1.y); u[6] = f2bf(v1.z); u[7] = f2bf(v1.w);
      } else {
#pragma unroll
        for (int j = 0; j < 8; ++j) u[j] = 0;
      }
      *(ushort8*)(ws + WS_W1BF + (unsigned)g * 16) = u;
    }
  } else if (blk < 40) {        // W2 image: [n 0..511][c' 0..15], c = c'^(n&7), kpad->0
    for (int g = (blk - 32) * 256 + tid; g < 8192; g += 8 * 256) {
      int n = g >> 4, cp = g & 15, c = cp ^ (n & 7);
      ushort8 u;
#pragma unroll
      for (int j = 0; j < 8; ++j) {
        int k = c * 8 + j;
        u[j] = (k < 120) ? f2bf(w2[n * 120 + k]) : (unsigned short)0;
      }
      *(ushort8*)(ws + WS_W2BF + (unsigned)g * 16) = u;
    }
  } else if (blk == 40) {       // G image: B-frag order [t][lane][8], q=lane&15
    for (int e = tid; e < 1024; e += 256) {
      int t = e >> 6, lane = e & 63, q = lane & 15, l4 = lane >> 4;
      ushort8 u;
#pragma unroll
      for (int j = 0; j < 8; ++j) {
        int k = t * 32 + l4 * 8 + j;
        float v = 0.f;
        if (q < 10) { int kk = q >> 1, c = q & 1; v = ln_g[k] * sms[kk * 1024 + k * 2 + c]; }
        u[j] = f2bf(v);
      }
      *(ushort8*)(ws + WS_GBF + (unsigned)e * 16) = u;
    }
  } else {                      // consts
    float* cst = (float*)(ws + WS_CONST);
    int lane = tid & 63, w = tid >> 6;
    for (int q = w; q < 10; q += 4) {
      int kk = q >> 1, c = q & 1;
      float s = 0.f;
#pragma unroll
      for (int i = 0; i < 8; ++i) { int k = lane + 64 * i; s += ln_b[k] * sms[kk * 1024 + k * 2 + c]; }
#pragma unroll
      for (int o = 32; o >= 1; o >>= 1) s += __shfl_xor(s, o);
      if (lane == 0) cst[q] = s + smb[kk * 2 + c];
    }
    if (tid == 0) cst[16] = tanhf(cs[0]);
    if (tid < 28) cst[32 + tid] = tanhf(embs[tid]);
  }
}

// ---------------------------------------------------------------------------
// K1: h1bf = relu(x @ W1^T + b1) as pre-swizzled bf16 image, 64 rows/block.
// 8 waves: wave w owns cols [16w,16w+16). W1 staged via global_load_lds from
// pre-swizzled image (zero VALU). x f32 loads reg-prefetched one K-step ahead.
// ---------------------------------------------------------------------------
__global__ __launch_bounds__(512) void k1_gemm1(
    const float* __restrict__ x, const unsigned char* __restrict__ w1bf,
    const float* __restrict__ b1, unsigned char* __restrict__ h1bf) {
  __shared__ unsigned char lds[24576];
  unsigned char* Xs = lds;            // [64 rows][128B] swz
  unsigned char* Ws = lds + 8192;     // [128 n][128B] swz (16 KB)

  const int tid = threadIdx.x, lane = tid & 63, w = tid >> 6;
  const int l15 = lane & 15, l4 = lane >> 4;
  const long row0 = (long)blockIdx.x * 64;

  const int xr = tid >> 3, xc8 = tid & 7;                 // x-stage: 8 els/thread
  const float* xsrc = x + (row0 + xr) * 1024 + xc8 * 8;
  unsigned char* xdst = Xs + xr * 128 + ((xc8 * 16) ^ ((xr & 7) << 4));
  const unsigned char* wsrc = w1bf + w * 2048 + lane * 16;
  unsigned char* wdst0 = Ws + w * 2048;

  const int col = w * 16 + l15;
  const float bias = (col < 120) ? b1[col] : 0.f;

  floatx4 acc[4];
#pragma unroll
  for (int i = 0; i < 4; ++i) acc[i] = floatx4{0.f, 0.f, 0.f, 0.f};

  float4 v0 = *(const float4*)(xsrc);
  float4 v1 = *(const float4*)(xsrc + 4);

  for (int ks = 0; ks < 16; ++ks) {
    __syncthreads();                       // prev MFMA reads complete
    gload16(wsrc + ks * 16384, wdst0);
    gload16(wsrc + ks * 16384 + 1024, wdst0 + 1024);
    ushort8 u;
    u[0] = f2bf(v0.x); u[1] = f2bf(v0.y); u[2] = f2bf(v0.z); u[3] = f2bf(v0.w);
    u[4] = f2bf(v1.x); u[5] = f2bf(v1.y); u[6] = f2bf(v1.z); u[7] = f2bf(v1.w);
    *(ushort8*)xdst = u;
    if (ks < 15) {                         // prefetch next K-step's x
      v0 = *(const float4*)(xsrc + (ks + 1) * 64);
      v1 = *(const float4*)(xsrc + (ks + 1) * 64 + 4);
    }
    __syncthreads();                       // drains gload vmcnt + ds_write
#pragma unroll
    for (int ss = 0; ss < 2; ++ss) {
      short8 a[4];
#pragma unroll
      for (int mt = 0; mt < 4; ++mt) {
        int r = mt * 16 + l15;
        a[mt] = *(const short8*)(Xs + r * 128 + ((ss * 64 + l4 * 16) ^ ((r & 7) << 4)));
      }
      short8 b = *(const short8*)(Ws + col * 128 + ((ss * 64 + l4 * 16) ^ ((col & 7) << 4)));
#pragma unroll
      for (int mt = 0; mt < 4; ++mt)
        acc[mt] = __builtin_amdgcn_mfma_f32_16x16x32_bf16(a[mt], b, acc[mt], 0, 0, 0);
    }
  }
  // epilogue: bias+relu -> swizzled bf16 image in LDS -> linear copy-out
  __syncthreads();
  unsigned char* h1s = lds;               // reuse, 16 KB
#pragma unroll
  for (int mt = 0; mt < 4; ++mt)
#pragma unroll
    for (int r = 0; r < 4; ++r) {
      int row = mt * 16 + l4 * 4 + r;
      float v = acc[mt][r] + bias;
      v = (col < 120) ? (v > 0.f ? v : 0.f) : 0.f;
      *(unsigned short*)(h1s + row * 256 + ((col * 2) ^ ((row & 7) << 4))) = f2bf(v);
    }
  __syncthreads();
  {
    const unsigned char* s = lds + tid * 32;
    unsigned char* d = h1bf + (long)blockIdx.x * 16384 + tid * 32;
    *(float4*)(d) = *(const float4*)(s);
    *(float4*)(d + 16) = *(const float4*)(s + 16);
  }
}

// ---------------------------------------------------------------------------
// K2: fused GEMM2 -> f32 LN stats -> normalized bf16 h2 -> GEMM3 (heads) ->
//     CE tail. 64 rows/block, 8 waves. All staging via global_load_lds.
// LDS (147456 dyn): phaseA h1s[0,16K) W2s[16K,144K);
//                   phaseB h2s[0,64K) Gs[64K,80K) stats[80K..) musig, Af
// ---------------------------------------------------------------------------
__global__ __launch_bounds__(512) void k2_fused(
    const unsigned char* __restrict__ h1bf, const unsigned char* __restrict__ w2bf,
    const unsigned char* __restrict__ gbf, const float* __restrict__ cst,
    const float* __restrict__ b2, const int* __restrict__ labels,
    const int* __restrict__ domain, float* __restrict__ out,
    float* __restrict__ partials) {
  extern __shared__ unsigned char lds[];
  unsigned char* h1s = lds;                  // [0,16384)
  unsigned char* W2s = lds + 16384;          // [16384,147456)
  unsigned char* h2s = lds;                  // phase B: [0,65536)
  unsigned char* Gs  = lds + 65536;          // [65536,81920)
  float* stats = (float*)(lds + 81920);      // [64][20] f32 (w*2, w*2+1 used)
  float* musig = (float*)(lds + 87040);      // [64][2]
  float* Af    = (float*)(lds + 87552);      // [64][20] f32

  const int tid = threadIdx.x, lane = tid & 63, w = tid >> 6;
  const int l15 = lane & 15, l4 = lane >> 4;
  const long row0 = (long)blockIdx.x * 64;
  const int n0 = w * 64;

  // ---- stage h1 tile + W2 via global_load_lds (pre-swizzled images)
  {
    const unsigned char* hs = h1bf + (long)blockIdx.x * 16384 + w * 2048 + lane * 16;
    gload16(hs, h1s + w * 2048);
    gload16(hs + 1024, h1s + w * 2048 + 1024);
    const unsigned char* wsrc = w2bf + w * 16384 + lane * 16;
#pragma unroll
    for (int i = 0; i < 16; ++i)
      gload16(wsrc + i * 1024, W2s + w * 16384 + i * 1024);
  }
  float b2v[4];
#pragma unroll
  for (int nt = 0; nt < 4; ++nt) b2v[nt] = b2[n0 + nt * 16 + l15];
  __syncthreads();

  // ---- GEMM2: 64 rows x 64 cols per wave, K=128
  floatx4 acc[4][4];
#pragma unroll
  for (int i = 0; i < 4; ++i)
#pragma unroll
    for (int j = 0; j < 4; ++j) acc[i][j] = floatx4{0.f, 0.f, 0.f, 0.f};
#pragma unroll
  for (int ks = 0; ks < 4; ++ks) {
    short8 a[4], b[4];
#pragma unroll
    for (int mt = 0; mt < 4; ++mt) {
      int r = mt * 16 + l15;
      a[mt] = *(const short8*)(h1s + r * 256 + ((ks * 64 + l4 * 16) ^ ((r & 7) << 4)));
    }
#pragma unroll
    for (int nt = 0; nt < 4; ++nt) {
      int n = n0 + nt * 16 + l15;
      b[nt] = *(const short8*)(W2s + n * 256 + ((ks * 64 + l4 * 16) ^ ((n & 7) << 4)));
    }
#pragma unroll
    for (int mt = 0; mt < 4; ++mt)
#pragma unroll
      for (int nt = 0; nt < 4; ++nt)
        acc[mt][nt] = __builtin_amdgcn_mfma_f32_16x16x32_bf16(a[mt], b[nt], acc[mt][nt], 0, 0, 0);
  }
  __syncthreads();   // all frag reads done; h1s/W2s regions reusable

  // ---- bias+relu in regs; issue Gs gloads; LN stats partials
  {
    const unsigned char* gs = gbf + w * 2048 + lane * 16;
    gload16(gs, Gs + w * 2048);
    gload16(gs + 1024, Gs + w * 2048 + 1024);
  }
#pragma unroll
  for (int mt = 0; mt < 4; ++mt)
#pragma unroll
    for (int nt = 0; nt < 4; ++nt)
#pragma unroll
      for (int r = 0; r < 4; ++r) {
        float v = acc[mt][nt][r] + b2v[nt];
        acc[mt][nt][r] = v > 0.f ? v : 0.f;
      }
#pragma unroll
  for (int mt = 0; mt < 4; ++mt)
#pragma unroll
    for (int r = 0; r < 4; ++r) {
      float s = 0.f, q2 = 0.f;
#pragma unroll
      for (int nt = 0; nt < 4; ++nt) { float v = acc[mt][nt][r]; s += v; q2 += v * v; }
#pragma unroll
      for (int o = 1; o <= 8; o <<= 1) { s += __shfl_xor(s, o); q2 += __shfl_xor(q2, o); }
      if (l15 == 0) {
        int row = mt * 16 + l4 * 4 + r;
        stats[row * 20 + w * 2] = s;
        stats[row * 20 + w * 2 + 1] = q2;
      }
    }
  __syncthreads();   // stats visible; Gs loaded

  if (tid < 64) {
    float S = 0.f, Q = 0.f;
#pragma unroll
    for (int j = 0; j < 8; ++j) { S += stats[tid * 20 + j * 2]; Q += stats[tid * 20 + j * 2 + 1]; }
    float mu = S * (1.f / 512.f);
    float var = Q * (1.f / 512.f) - mu * mu;
    musig[tid * 2] = mu;
    musig[tid * 2 + 1] = rsqrtf(var + 1e-5f);
  }
  __syncthreads();

  // ---- write normalized h2 as bf16 (swizzled) for GEMM3 A-frags
#pragma unroll
  for (int mt = 0; mt < 4; ++mt)
#pragma unroll
    for (int r = 0; r < 4; ++r) {
      int row = mt * 16 + l4 * 4 + r;
      float mu = musig[row * 2], rs = musig[row * 2 + 1];
#pragma unroll
      for (int nt = 0; nt < 4; ++nt) {
        int colc = n0 + nt * 16 + l15;
        float hn = (acc[mt][nt][r] - mu) * rs;
        *(unsigned short*)(h2s + row * 1024 + ((colc * 2) ^ ((row & 7) << 4))) = f2bf(hn);
      }
    }
  __syncthreads();

  // ---- GEMM3: A[64][16] = h2n @ G^T ; waves 0..3, wave = m-tile, full K=512
  if (w < 4) {
    floatx4 a3 = floatx4{0.f, 0.f, 0.f, 0.f};
    int row = w * 16 + l15;
#pragma unroll
    for (int t = 0; t < 16; ++t) {
      short8 aa = *(const short8*)(h2s + row * 1024 + ((t * 64 + l4 * 16) ^ ((row & 7) << 4)));
      short8 bb = *(const short8*)(Gs + t * 1024 + lane * 16);
      a3 = __builtin_amdgcn_mfma_f32_16x16x32_bf16(aa, bb, a3, 0, 0, 0);
    }
#pragma unroll
    for (int reg = 0; reg < 4; ++reg) {
      int orow = w * 16 + l4 * 4 + reg;
      Af[orow * 20 + l15] = a3[reg];
    }
  }
  __syncthreads();

  // ---- tail: per-row logits, CE, partial sums (wave 0)
  if (tid < 64) {
    long grow = row0 + tid;
    float pd[10];
#pragma unroll
    for (int q = 0; q < 10; ++q) pd[q] = Af[tid * 20 + q] + cst[q];
    int lab = labels[grow], dm = domain[grow];
    float cw0 = cst[16];
    float ls0 = cw0 * pd[0], ls1 = cw0 * pd[1];
#pragma unroll
    for (int kk = 1; kk < 5; ++kk) {
      float c = cst[32 + dm * 4 + kk - 1];
      ls0 += c * pd[kk * 2];
      ls1 += c * pd[kk * 2 + 1];
    }
    float lc0 = pd[0], lc1 = pd[1];
    out[1 + grow * 2 + 0] = lc0;
    out[1 + grow * 2 + 1] = lc1;
    float m1 = fmaxf(lc0, lc1);
    float lse1 = m1 + logf(expf(lc0 - m1) + expf(lc1 - m1));
    float nllc = lse1 - (lab ? lc1 : lc0);
    float m2 = fmaxf(ls0, ls1);
    float lse2 = m2 + logf(expf(ls0 - m2) + expf(ls1 - m2));
    float nlls = lse2 - (lab ? ls1 : ls0);
    float wl = lab ? 0.9f : 0.1f;
    float wsum = wl, scom = wl * nllc, sspec = wl * nlls;
#pragma unroll
    for (int o = 32; o >= 1; o >>= 1) {
      wsum += __shfl_xor(wsum, o);
      scom += __shfl_xor(scom, o);
      sspec += __shfl_xor(sspec, o);
    }
    if (tid == 0) {
      partials[(long)blockIdx.x * 4] = wsum;
      partials[(long)blockIdx.x * 4 + 1] = scom;
      partials[(long)blockIdx.x * 4 + 2] = sspec;
    }
  }
}

// ---------------------------------------------------------------------------
// K3: deterministic final reduce + orth loss (exact f32) + scalars.
// ---------------------------------------------------------------------------
__global__ __launch_bounds__(256) void k3_finalize(
    const float* __restrict__ partials, const float* __restrict__ sms,
    float* __restrict__ out) {
  __shared__ float wsums[4][3];
  __shared__ float ow[4];
  const int tid = threadIdx.x;
  const int lane = tid & 63, wid = tid >> 6;
  float sw = 0.f, sc = 0.f, ss = 0.f;
  for (int i = tid; i < 1024; i += 256) {
    sw += partials[i * 4];
    sc += partials[i * 4 + 1];
    ss += partials[i * 4 + 2];
  }
#pragma unroll
  for (int o = 32; o >= 1; o >>= 1) {
    sw += __shfl_xor(sw, o);
    sc += __shfl_xor(sc, o);
    ss += __shfl_xor(ss, o);
  }
  if (lane == 0) { wsums[wid][0] = sw; wsums[wid][1] = sc; wsums[wid][2] = ss; }

  float osum = 0.f;
  for (int p = wid; p < 50; p += 4) {
    int c = p / 25, kk = (p / 5) % 5, j = p % 5;
    float acc = 0.f;
#pragma unroll
    for (int hh = 0; hh < 8; ++hh) {
      int h = lane + 64 * hh;
      acc += sms[kk * 1024 + h * 2 + c] * sms[j * 1024 + h * 2 + c];
    }
#pragma unroll
    for (int o = 32; o >= 1; o >>= 1) acc += __shfl_xor(acc, o);
    float d = acc - ((kk == j) ? 1.f : 0.f);
    osum += d * d;
  }
  if (lane == 0) ow[wid] = osum;
  __syncthreads();
  if (tid == 0) {
    float SW = 0.f, SC = 0.f, SS = 0.f, OS = 0.f;
    for (int w = 0; w < 4; ++w) {
      SW += wsums[w][0]; SC += wsums[w][1]; SS += wsums[w][2]; OS += ow[w];
    }
    float orth = OS * (1.f / 50.f);
    float cls = SC / SW;
    float spec = SS / SW;
    out[0] = cls + spec + orth;
    out[131073] = cls;
    out[131074] = spec;
    out[131075] = orth;
  }
}

extern "C" void kernel_launch(void* const* d_in, const int* in_sizes, int n_in,
                              void* d_out, int out_size, void* d_ws, size_t ws_size,
                              hipStream_t stream) {
  const float* x      = (const float*)d_in[0];
  const int* labels   = (const int*)d_in[1];
  const int* domain   = (const int*)d_in[2];
  const float* fc1_w  = (const float*)d_in[3];
  const float* fc1_b  = (const float*)d_in[4];
  const float* fc2_w  = (const float*)d_in[5];
  const float* fc2_b  = (const float*)d_in[6];
  const float* ln_g   = (const float*)d_in[7];
  const float* ln_b   = (const float*)d_in[8];
  const float* sms    = (const float*)d_in[9];
  const float* sm_b   = (const float*)d_in[10];
  const float* embs   = (const float*)d_in[11];
  const float* cs_wt  = (const float*)d_in[12];
  float* out = (float*)d_out;
  unsigned char* ws = (unsigned char*)d_ws;

  (void)hipFuncSetAttribute((const void*)k2_fused,
                            hipFuncAttributeMaxDynamicSharedMemorySize, 147456);

  hipLaunchKernelGGL(k0_prep, dim3(42), dim3(256), 0, stream,
                     fc1_w, fc2_w, ln_g, ln_b, sms, sm_b, embs, cs_wt, ws);
  hipLaunchKernelGGL(k1_gemm1, dim3(BTOT / 64), dim3(512), 0, stream,
                     x, ws + WS_W1BF, fc1_b, ws + WS_H1BF);
  hipLaunchKernelGGL(k2_fused, dim3(BTOT / 64), dim3(512), 147456, stream,
                     ws + WS_H1BF, ws + WS_W2BF, ws + WS_GBF,
                     (const float*)(ws + WS_CONST), fc2_b,
                     labels, domain, out, (float*)(ws + WS_PART));
  hipLaunchKernelGGL(k3_finalize, dim3(1), dim3(256), 0, stream,
                     (const float*)(ws + WS_PART), sms, out);
}

// Round 5
// 109.892 us; speedup vs baseline: 1.8884x; 1.0316x over previous
//
#include <hip/hip_runtime.h>
#include <hip/hip_bf16.h>

typedef __attribute__((ext_vector_type(8))) short short8;        // 8 bf16 MFMA A/B frag
typedef __attribute__((ext_vector_type(4))) float floatx4;       // MFMA C/D frag
typedef __attribute__((ext_vector_type(8))) unsigned short ushort8;

#define BTOT 65536
// ws byte offsets
#define WS_W1BF   0u          // 256 KB: [16 ks][16384B] pre-swizzled LDS image of W1 bf16
#define WS_W2BF   262144u     // 128 KB: frag-ordered W2 bf16: [(w*4+ks)*4+nt][lane][16B]
#define WS_GBF    393216u     // 16 KB: B-frag image of G[q][k] = ln_g*sms
#define WS_CONST  409600u     // 64 f32: [0..9]=Cb', [16]=tanh(cs), [32..59]=tanh(embs)
#define WS_H1BF   524288u     // 16 MB: 1024 blocks x 16384B pre-swizzled h1 bf16
#define WS_PART   17301504u   // 1024 x 4 f32 partials

__device__ __forceinline__ unsigned short f2bf(float f) {
  unsigned u = __float_as_uint(f);
  unsigned r = u + 0x7FFFu + ((u >> 16) & 1u);   // RNE
  return (unsigned short)(r >> 16);
}

__device__ __forceinline__ void gload16(const void* g, void* l) {
  __builtin_amdgcn_global_load_lds(
      (const __attribute__((address_space(1))) unsigned int*)g,
      (__attribute__((address_space(3))) unsigned int*)l, 16, 0, 0);
}

// ---------------------------------------------------------------------------
// K0: one-shot prep. W1 pre-swizzled LDS image, W2 + G frag-ordered images,
// constants Cb' and tanh tables.
// ---------------------------------------------------------------------------
__global__ __launch_bounds__(256) void k0_prep(
    const float* __restrict__ w1, const float* __restrict__ w2,
    const float* __restrict__ ln_g, const float* __restrict__ ln_b,
    const float* __restrict__ sms, const float* __restrict__ smb,
    const float* __restrict__ embs, const float* __restrict__ cs,
    unsigned char* __restrict__ ws) {
  const int blk = blockIdx.x, tid = threadIdx.x;
  if (blk < 32) {               // W1 image: [ks][n 0..127][chunk c'], c = c'^(n&7)
    for (int g = blk * 256 + tid; g < 16384; g += 32 * 256) {
      int ks = g >> 10, d = g & 1023;
      int n = d >> 3, cp = d & 7, c = cp ^ (n & 7);
      ushort8 u;
      if (n < 120) {
        const float* s = w1 + n * 1024 + ks * 64 + c * 8;
        float4 v0 = *(const float4*)s, v1 = *(const float4*)(s + 4);
        u[0] = f2bf(v0.x); u[1] = f2bf(v0.y); u[2] = f2bf(v0.z); u[3] = f2bf(v0.w);
        u[4] = f2bf(v1.x); u[5] = f2bf(v1.y); u[6] = f2bf(v1.z); u[7] = f2bf(v1.w);
      } else {
#pragma unroll
        for (int j = 0; j < 8; ++j) u[j] = 0;
      }
      *(ushort8*)(ws + WS_W1BF + (unsigned)g * 16) = u;
    }
  } else if (blk < 40) {        // W2 frag image: 8192 x 16B, frag f=(w*4+ks)*4+nt
    for (int g = (blk - 32) * 256 + tid; g < 8192; g += 8 * 256) {
      int lane = g & 63, f = g >> 6;
      int nt = f & 3, ks = (f >> 2) & 3, w = f >> 4;
      int n = w * 64 + nt * 16 + (lane & 15);
      ushort8 u;
#pragma unroll
      for (int j = 0; j < 8; ++j) {
        // B-frag k index for 16x16x32: K=32 per ks step (FIX: was ks*64)
        int k = ks * 32 + (lane >> 4) * 8 + j;
        u[j] = (k < 120) ? f2bf(w2[n * 120 + k]) : (unsigned short)0;
      }
      *(ushort8*)(ws + WS_W2BF + (unsigned)g * 16) = u;
    }
  } else if (blk == 40) {       // G frag image: [t][lane][16B], q=lane&15
    for (int e = tid; e < 1024; e += 256) {
      int t = e >> 6, lane = e & 63, q = lane & 15;
      ushort8 u;
#pragma unroll
      for (int j = 0; j < 8; ++j) {
        int k = t * 32 + (lane >> 4) * 8 + j;
        float v = 0.f;
        if (q < 10) { int kk = q >> 1, c = q & 1; v = ln_g[k] * sms[kk * 1024 + k * 2 + c]; }
        u[j] = f2bf(v);
      }
      *(ushort8*)(ws + WS_GBF + (unsigned)e * 16) = u;
    }
  } else {                      // consts
    float* cst = (float*)(ws + WS_CONST);
    int lane = tid & 63, w = tid >> 6;
    for (int q = w; q < 10; q += 4) {
      int kk = q >> 1, c = q & 1;
      float s = 0.f;
#pragma unroll
      for (int i = 0; i < 8; ++i) { int k = lane + 64 * i; s += ln_b[k] * sms[kk * 1024 + k * 2 + c]; }
#pragma unroll
      for (int o = 32; o >= 1; o >>= 1) s += __shfl_xor(s, o);
      if (lane == 0) cst[q] = s + smb[kk * 2 + c];
    }
    if (tid == 0) cst[16] = tanhf(cs[0]);
    if (tid < 28) cst[32 + tid] = tanhf(embs[tid]);
  }
}

// ---------------------------------------------------------------------------
// K1: h1bf = relu(x @ W1^T + b1), 64 rows/block, 8 waves (wave = 16-col slice).
// Double-buffered X/W LDS, ONE raw s_barrier per K-step with counted vmcnt:
//   per step t: gload W(t+1)->Wbuf^ ; ds_write x(t+1)->Xbuf^ ; issue x(t+2);
//               MFMA(t); s_waitcnt vmcnt(2) lgkmcnt(0); s_barrier.
// vmcnt(2): oldest-2 outstanding = the W gloads (sched_barrier pins order);
// the 2 x(t+2) loads stay in flight across the barrier.
// ---------------------------------------------------------------------------
__global__ __launch_bounds__(512) void k1_gemm1(
    const float* __restrict__ x, const unsigned char* __restrict__ w1bf,
    const float* __restrict__ b1, unsigned char* __restrict__ h1bf) {
  __shared__ unsigned char lds[49152];
  // Xbuf[b] = lds + b*8192 ; Wbuf[b] = lds + 16384 + b*16384
  const int tid = threadIdx.x, lane = tid & 63, w = tid >> 6;
  const int l15 = lane & 15, l4 = lane >> 4;
  const long row0 = (long)blockIdx.x * 64;

  const int xr = tid >> 3, xc8 = tid & 7;                 // x-stage: 8 f32/thread
  const float* xsrc = x + (row0 + xr) * 1024 + xc8 * 8;
  const unsigned xoff = (unsigned)(xr * 128 + ((xc8 * 16) ^ ((xr & 7) << 4)));
  const unsigned char* wsrc = w1bf + w * 2048 + lane * 16;
  const unsigned wdstoff = 16384u + (unsigned)w * 2048;

  const int col = w * 16 + l15;
  const float bias = (col < 120) ? b1[col] : 0.f;

  floatx4 acc[4];
#pragma unroll
  for (int i = 0; i < 4; ++i) acc[i] = floatx4{0.f, 0.f, 0.f, 0.f};

  // ---- prologue: stage step 0, preload x(1)
  float4 v0 = *(const float4*)(xsrc);
  float4 v1 = *(const float4*)(xsrc + 4);
  gload16(wsrc, lds + wdstoff);
  gload16(wsrc + 1024, lds + wdstoff + 1024);
  __builtin_amdgcn_sched_barrier(0);
  {
    ushort8 u;
    u[0] = f2bf(v0.x); u[1] = f2bf(v0.y); u[2] = f2bf(v0.z); u[3] = f2bf(v0.w);
    u[4] = f2bf(v1.x); u[5] = f2bf(v1.y); u[6] = f2bf(v1.z); u[7] = f2bf(v1.w);
    *(ushort8*)(lds + xoff) = u;
  }
  v0 = *(const float4*)(xsrc + 64);
  v1 = *(const float4*)(xsrc + 68);
  __builtin_amdgcn_sched_barrier(0);
  asm volatile("s_waitcnt vmcnt(2) lgkmcnt(0)" ::: "memory");
  __builtin_amdgcn_s_barrier();

  for (int ks = 0; ks < 16; ++ks) {
    const unsigned cur = ks & 1u, nxt = cur ^ 1u;
    // A: next W tile gloads (oldest outstanding at step end)
    if (ks < 15) {
      gload16(wsrc + (ks + 1) * 16384, lds + 16384 + nxt * 16384 + (wdstoff - 16384));
      gload16(wsrc + (ks + 1) * 16384 + 1024, lds + 16384 + nxt * 16384 + (wdstoff - 16384) + 1024);
    }
    __builtin_amdgcn_sched_barrier(0);
    // B: ds_write x(ks+1) from regs (auto vmcnt wait on v0/v1)
    if (ks < 15) {
      ushort8 u;
      u[0] = f2bf(v0.x); u[1] = f2bf(v0.y); u[2] = f2bf(v0.z); u[3] = f2bf(v0.w);
      u[4] = f2bf(v1.x); u[5] = f2bf(v1.y); u[6] = f2bf(v1.z); u[7] = f2bf(v1.w);
      *(ushort8*)(lds + nxt * 8192 + xoff) = u;
    }
    // C: issue x(ks+2) loads (newest outstanding; fly across the barrier)
    if (ks < 14) {
      v0 = *(const float4*)(xsrc + (ks + 2) * 64);
      v1 = *(const float4*)(xsrc + (ks + 2) * 64 + 4);
    }
    __builtin_amdgcn_sched_barrier(0);
    // D: MFMA on current buffers
    const unsigned char* Xc = lds + cur * 8192;
    const unsigned char* Wc = lds + 16384 + cur * 16384;
#pragma unroll
    for (int ss = 0; ss < 2; ++ss) {
      short8 a[4];
#pragma unroll
      for (int mt = 0; mt < 4; ++mt) {
        int r = mt * 16 + l15;
        a[mt] = *(const short8*)(Xc + r * 128 + ((ss * 64 + l4 * 16) ^ ((r & 7) << 4)));
      }
      short8 b = *(const short8*)(Wc + col * 128 + ((ss * 64 + l4 * 16) ^ ((col & 7) << 4)));
#pragma unroll
      for (int mt = 0; mt < 4; ++mt)
        acc[mt] = __builtin_amdgcn_mfma_f32_16x16x32_bf16(a[mt], b, acc[mt], 0, 0, 0);
    }
    // E: counted wait + raw barrier (x(ks+2) loads remain in flight)
    if (ks < 14) {
      asm volatile("s_waitcnt vmcnt(2) lgkmcnt(0)" ::: "memory");
    } else {
      asm volatile("s_waitcnt vmcnt(0) lgkmcnt(0)" ::: "memory");
    }
    __builtin_amdgcn_s_barrier();
  }

  // epilogue: bias+relu -> swizzled bf16 image in LDS -> linear copy-out
  unsigned char* h1s = lds;               // [0,16384) safe: all reads barriered
#pragma unroll
  for (int mt = 0; mt < 4; ++mt)
#pragma unroll
    for (int r = 0; r < 4; ++r) {
      int row = mt * 16 + l4 * 4 + r;
      float v = acc[mt][r] + bias;
      v = (col < 120) ? (v > 0.f ? v : 0.f) : 0.f;
      *(unsigned short*)(h1s + row * 256 + ((col * 2) ^ ((row & 7) << 4))) = f2bf(v);
    }
  __syncthreads();
  {
    const unsigned char* s = lds + tid * 32;
    unsigned char* d = h1bf + (long)blockIdx.x * 16384 + tid * 32;
    *(float4*)(d) = *(const float4*)(s);
    *(float4*)(d + 16) = *(const float4*)(s + 16);
  }
}

// ---------------------------------------------------------------------------
// K2: fused GEMM2 -> LN -> GEMM3 (heads) -> CE tail. 64 rows/block, 8 waves.
// W2 and G consumed as frag-ordered REGISTER operands straight from L2-resident
// global images (no LDS stage). LDS 76800B -> 2 blocks/CU.
// LDS: [0,16K) h1s (phase A)  |  [0,64K) h2s (phase B, aliases h1s)
//      [64K, ..) stats/musig/Af
// ---------------------------------------------------------------------------
__global__ __launch_bounds__(512, 4) void k2_fused(
    const unsigned char* __restrict__ h1bf, const unsigned char* __restrict__ w2f,
    const unsigned char* __restrict__ gbf, const float* __restrict__ cst,
    const float* __restrict__ b2, const int* __restrict__ labels,
    const int* __restrict__ domain, float* __restrict__ out,
    float* __restrict__ partials) {
  extern __shared__ unsigned char lds[];
  unsigned char* h1s = lds;                  // [0,16384)
  unsigned char* h2s = lds;                  // phase B: [0,65536)
  float* stats = (float*)(lds + 65536);      // [64][20]
  float* musig = (float*)(lds + 70656);      // [64][2]
  float* Af    = (float*)(lds + 71168);      // [64][20]

  const int tid = threadIdx.x, lane = tid & 63, w = tid >> 6;
  const int l15 = lane & 15, l4 = lane >> 4;
  const long row0 = (long)blockIdx.x * 64;
  const int n0 = w * 64;

  // ---- stage h1 tile (16 KB) via global_load_lds
  {
    const unsigned char* hs = h1bf + (long)blockIdx.x * 16384 + w * 2048 + lane * 16;
    gload16(hs, h1s + w * 2048);
    gload16(hs + 1024, h1s + w * 2048 + 1024);
  }
  float b2v[4];
#pragma unroll
  for (int nt = 0; nt < 4; ++nt) b2v[nt] = b2[n0 + nt * 16 + l15];
  __syncthreads();

  // ---- GEMM2: 64 rows x 64 cols per wave, K=128; B-frags from global image
  floatx4 acc[4][4];
#pragma unroll
  for (int i = 0; i < 4; ++i)
#pragma unroll
    for (int j = 0; j < 4; ++j) acc[i][j] = floatx4{0.f, 0.f, 0.f, 0.f};
#pragma unroll
  for (int ks = 0; ks < 4; ++ks) {
    short8 a[4], b[4];
#pragma unroll
    for (int nt = 0; nt < 4; ++nt)
      b[nt] = *(const short8*)(w2f + (((w * 4 + ks) * 4 + nt) * 64 + lane) * 16);
#pragma unroll
    for (int mt = 0; mt < 4; ++mt) {
      int r = mt * 16 + l15;
      a[mt] = *(const short8*)(h1s + r * 256 + ((ks * 64 + l4 * 16) ^ ((r & 7) << 4)));
    }
#pragma unroll
    for (int mt = 0; mt < 4; ++mt)
#pragma unroll
      for (int nt = 0; nt < 4; ++nt)
        acc[mt][nt] = __builtin_amdgcn_mfma_f32_16x16x32_bf16(a[mt], b[nt], acc[mt][nt], 0, 0, 0);
  }

  // ---- bias+relu in regs; LN stats partials (l15-group reduce)
#pragma unroll
  for (int mt = 0; mt < 4; ++mt)
#pragma unroll
    for (int nt = 0; nt < 4; ++nt)
#pragma unroll
      for (int r = 0; r < 4; ++r) {
        float v = acc[mt][nt][r] + b2v[nt];
        acc[mt][nt][r] = v > 0.f ? v : 0.f;
      }
#pragma unroll
  for (int mt = 0; mt < 4; ++mt)
#pragma unroll
    for (int r = 0; r < 4; ++r) {
      float s = 0.f, q2 = 0.f;
#pragma unroll
      for (int nt = 0; nt < 4; ++nt) { float v = acc[mt][nt][r]; s += v; q2 += v * v; }
#pragma unroll
      for (int o = 1; o <= 8; o <<= 1) { s += __shfl_xor(s, o); q2 += __shfl_xor(q2, o); }
      if (l15 == 0) {
        int row = mt * 16 + l4 * 4 + r;
        stats[row * 20 + w * 2] = s;
        stats[row * 20 + w * 2 + 1] = q2;
      }
    }
  __syncthreads();   // stats visible; h1s reads done (h2s may alias)

  if (tid < 64) {
    float S = 0.f, Q = 0.f;
#pragma unroll
    for (int j = 0; j < 8; ++j) { S += stats[tid * 20 + j * 2]; Q += stats[tid * 20 + j * 2 + 1]; }
    float mu = S * (1.f / 512.f);
    float var = Q * (1.f / 512.f) - mu * mu;
    musig[tid * 2] = mu;
    musig[tid * 2 + 1] = rsqrtf(var + 1e-5f);
  }
  __syncthreads();

  // ---- write normalized h2 as bf16 (swizzled) for GEMM3 A-frags
#pragma unroll
  for (int mt = 0; mt < 4; ++mt)
#pragma unroll
    for (int r = 0; r < 4; ++r) {
      int row = mt * 16 + l4 * 4 + r;
      float mu = musig[row * 2], rs = musig[row * 2 + 1];
#pragma unroll
      for (int nt = 0; nt < 4; ++nt) {
        int colc = n0 + nt * 16 + l15;
        float hn = (acc[mt][nt][r] - mu) * rs;
        *(unsigned short*)(h2s + row * 1024 + ((colc * 2) ^ ((row & 7) << 4))) = f2bf(hn);
      }
    }
  __syncthreads();

  // ---- GEMM3: A[64][10] = h2n @ G^T ; waves 0..3, K=512; B-frags from global
  if (w < 4) {
    floatx4 a3 = floatx4{0.f, 0.f, 0.f, 0.f};
    int row = w * 16 + l15;
#pragma unroll
    for (int t = 0; t < 16; ++t) {
      short8 aa = *(const short8*)(h2s + row * 1024 + ((t * 64 + l4 * 16) ^ ((row & 7) << 4)));
      short8 bb = *(const short8*)(gbf + t * 1024 + lane * 16);
      a3 = __builtin_amdgcn_mfma_f32_16x16x32_bf16(aa, bb, a3, 0, 0, 0);
    }
#pragma unroll
    for (int reg = 0; reg < 4; ++reg) {
      int orow = w * 16 + l4 * 4 + reg;
      if (l15 < 10) Af[orow * 20 + l15] = a3[reg];
    }
  }
  __syncthreads();

  // ---- tail: per-row logits, CE, partial sums (wave 0)
  if (tid < 64) {
    long grow = row0 + tid;
    float pd[10];
#pragma unroll
    for (int q = 0; q < 10; ++q) pd[q] = Af[tid * 20 + q] + cst[q];
    int lab = labels[grow], dm = domain[grow];
    float cw0 = cst[16];
    float ls0 = cw0 * pd[0], ls1 = cw0 * pd[1];
#pragma unroll
    for (int kk = 1; kk < 5; ++kk) {
      float c = cst[32 + dm * 4 + kk - 1];
      ls0 += c * pd[kk * 2];
      ls1 += c * pd[kk * 2 + 1];
    }
    float lc0 = pd[0], lc1 = pd[1];
    *(float2*)(out + 1 + grow * 2) = float2{lc0, lc1};
    // 2-class LSE: lse = max + log(1 + exp(min - max))
    float m1 = fmaxf(lc0, lc1), n1 = fminf(lc0, lc1);
    float lse1 = m1 + logf(1.f + expf(n1 - m1));
    float nllc = lse1 - (lab ? lc1 : lc0);
    float m2 = fmaxf(ls0, ls1), n2 = fminf(ls0, ls1);
    float lse2 = m2 + logf(1.f + expf(n2 - m2));
    float nlls = lse2 - (lab ? ls1 : ls0);
    float wl = lab ? 0.9f : 0.1f;
    float wsum = wl, scom = wl * nllc, sspec = wl * nlls;
#pragma unroll
    for (int o = 32; o >= 1; o >>= 1) {
      wsum += __shfl_xor(wsum, o);
      scom += __shfl_xor(scom, o);
      sspec += __shfl_xor(sspec, o);
    }
    if (tid == 0) {
      partials[(long)blockIdx.x * 4] = wsum;
      partials[(long)blockIdx.x * 4 + 1] = scom;
      partials[(long)blockIdx.x * 4 + 2] = sspec;
    }
  }
}

// ---------------------------------------------------------------------------
// K3: deterministic final reduce + orth loss (exact f32) + scalars.
// ---------------------------------------------------------------------------
__global__ __launch_bounds__(256) void k3_finalize(
    const float* __restrict__ partials, const float* __restrict__ sms,
    float* __restrict__ out) {
  __shared__ float wsums[4][3];
  __shared__ float ow[4];
  const int tid = threadIdx.x;
  const int lane = tid & 63, wid = tid >> 6;
  float sw = 0.f, sc = 0.f, ss = 0.f;
  for (int i = tid; i < 1024; i += 256) {
    sw += partials[i * 4];
    sc += partials[i * 4 + 1];
    ss += partials[i * 4 + 2];
  }
#pragma unroll
  for (int o = 32; o >= 1; o >>= 1) {
    sw += __shfl_xor(sw, o);
    sc += __shfl_xor(sc, o);
    ss += __shfl_xor(ss, o);
  }
  if (lane == 0) { wsums[wid][0] = sw; wsums[wid][1] = sc; wsums[wid][2] = ss; }

  float osum = 0.f;
  for (int p = wid; p < 50; p += 4) {
    int c = p / 25, kk = (p / 5) % 5, j = p % 5;
    float acc = 0.f;
#pragma unroll
    for (int hh = 0; hh < 8; ++hh) {
      int h = lane + 64 * hh;
      acc += sms[kk * 1024 + h * 2 + c] * sms[j * 1024 + h * 2 + c];
    }
#pragma unroll
    for (int o = 32; o >= 1; o >>= 1) acc += __shfl_xor(acc, o);
    float d = acc - ((kk == j) ? 1.f : 0.f);
    osum += d * d;
  }
  if (lane == 0) ow[wid] = osum;
  __syncthreads();
  if (tid == 0) {
    float SW = 0.f, SC = 0.f, SS = 0.f, OS = 0.f;
    for (int w = 0; w < 4; ++w) {
      SW += wsums[w][0]; SC += wsums[w][1]; SS += wsums[w][2]; OS += ow[w];
    }
    float orth = OS * (1.f / 50.f);
    float cls = SC / SW;
    float spec = SS / SW;
    out[0] = cls + spec + orth;
    out[131073] = cls;
    out[131074] = spec;
    out[131075] = orth;
  }
}

extern "C" void kernel_launch(void* const* d_in, const int* in_sizes, int n_in,
                              void* d_out, int out_size, void* d_ws, size_t ws_size,
                              hipStream_t stream) {
  const float* x      = (const float*)d_in[0];
  const int* labels   = (const int*)d_in[1];
  const int* domain   = (const int*)d_in[2];
  const float* fc1_w  = (const float*)d_in[3];
  const float* fc1_b  = (const float*)d_in[4];
  const float* fc2_w  = (const float*)d_in[5];
  const float* fc2_b  = (const float*)d_in[6];
  const float* ln_g   = (const float*)d_in[7];
  const float* ln_b   = (const float*)d_in[8];
  const float* sms    = (const float*)d_in[9];
  const float* sm_b   = (const float*)d_in[10];
  const float* embs   = (const float*)d_in[11];
  const float* cs_wt  = (const float*)d_in[12];
  float* out = (float*)d_out;
  unsigned char* ws = (unsigned char*)d_ws;

  (void)hipFuncSetAttribute((const void*)k2_fused,
                            hipFuncAttributeMaxDynamicSharedMemorySize, 76800);

  hipLaunchKernelGGL(k0_prep, dim3(42), dim3(256), 0, stream,
                     fc1_w, fc2_w, ln_g, ln_b, sms, sm_b, embs, cs_wt, ws);
  hipLaunchKernelGGL(k1_gemm1, dim3(BTOT / 64), dim3(512), 0, stream,
                     x, ws + WS_W1BF, fc1_b, ws + WS_H1BF);
  hipLaunchKernelGGL(k2_fused, dim3(BTOT / 64), dim3(512), 76800, stream,
                     ws + WS_H1BF, ws + WS_W2BF, ws + WS_GBF,
                     (const float*)(ws + WS_CONST), fc2_b,
                     labels, domain, out, (float*)(ws + WS_PART));
  hipLaunchKernelGGL(k3_finalize, dim3(1), dim3(256), 0, stream,
                     (const float*)(ws + WS_PART), sms, out);
}

// Round 6
// 104.747 us; speedup vs baseline: 1.9812x; 1.0491x over previous
//
#include <hip/hip_runtime.h>
#include <hip/hip_bf16.h>

typedef __attribute__((ext_vector_type(8))) short short8;        // 8 bf16 MFMA A/B frag
typedef __attribute__((ext_vector_type(4))) float floatx4;       // MFMA C/D frag
typedef __attribute__((ext_vector_type(8))) unsigned short ushort8;

#define BTOT 65536
// ws byte offsets
#define WS_W1BF   0u          // 256 KB: [16 ks][16384B] pre-swizzled LDS image of W1 bf16
#define WS_W2BF   262144u     // 128 KB: frag-ordered W2 bf16 (k-permuted to match h1 image)
#define WS_GBF    393216u     // 16 KB: B-frag image of G[q][k] (k-permuted to match h2 image)
#define WS_CONST  409600u     // 64 f32: [0..9]=Cb', [16]=tanh(cs), [32..59]=tanh(embs)
#define WS_H1BF   524288u     // 16 MB: 512 k1-blocks x 32768B k-permuted swizzled h1 bf16
#define WS_PART   17301504u   // 1024 x 4 f32 partials

__device__ __forceinline__ unsigned short f2bf(float f) {
  unsigned u = __float_as_uint(f);
  unsigned r = u + 0x7FFFu + ((u >> 16) & 1u);   // RNE
  return (unsigned short)(r >> 16);
}

__device__ __forceinline__ unsigned cvtpk(float lo, float hi) {
  unsigned r;
  asm("v_cvt_pk_bf16_f32 %0, %1, %2" : "=v"(r) : "v"(lo), "v"(hi));
  return r;
}

__device__ __forceinline__ void gload16(const void* g, void* l) {
  __builtin_amdgcn_global_load_lds(
      (const __attribute__((address_space(1))) unsigned int*)g,
      (__attribute__((address_space(3))) unsigned int*)l, 16, 0, 0);
}

// ---------------------------------------------------------------------------
// K0: one-shot prep. W1 pre-swizzled LDS image, W2 + G frag-ordered images
// (both with the k-permutation matching the packed h1/h2 producers),
// constants Cb' and tanh tables.
// ---------------------------------------------------------------------------
__global__ __launch_bounds__(256) void k0_prep(
    const float* __restrict__ w1, const float* __restrict__ w2,
    const float* __restrict__ ln_g, const float* __restrict__ ln_b,
    const float* __restrict__ sms, const float* __restrict__ smb,
    const float* __restrict__ embs, const float* __restrict__ cs,
    unsigned char* __restrict__ ws) {
  const int blk = blockIdx.x, tid = threadIdx.x;
  if (blk < 32) {               // W1 image: [ks][n 0..127][chunk c'], c = c'^(n&7)
    for (int g = blk * 256 + tid; g < 16384; g += 32 * 256) {
      int ks = g >> 10, d = g & 1023;
      int n = d >> 3, cp = d & 7, c = cp ^ (n & 7);
      ushort8 u;
      if (n < 120) {
        const float* s = w1 + n * 1024 + ks * 64 + c * 8;
        float4 v0 = *(const float4*)s, v1 = *(const float4*)(s + 4);
        u[0] = f2bf(v0.x); u[1] = f2bf(v0.y); u[2] = f2bf(v0.z); u[3] = f2bf(v0.w);
        u[4] = f2bf(v1.x); u[5] = f2bf(v1.y); u[6] = f2bf(v1.z); u[7] = f2bf(v1.w);
      } else {
#pragma unroll
        for (int j = 0; j < 8; ++j) u[j] = 0;
      }
      *(ushort8*)(ws + WS_W1BF + (unsigned)g * 16) = u;
    }
  } else if (blk < 40) {        // W2 frag image, k-permuted: kcol = (khat&7)*16 + (khat>>3)
    for (int g = (blk - 32) * 256 + tid; g < 8192; g += 8 * 256) {
      int lane = g & 63, f = g >> 6;
      int nt = f & 3, ks = (f >> 2) & 3, w = f >> 4;
      int n = w * 64 + nt * 16 + (lane & 15);
      ushort8 u;
#pragma unroll
      for (int j = 0; j < 8; ++j) {
        int khat = ks * 32 + (lane >> 4) * 8 + j;         // k-slot in h1 image
        int kcol = (khat & 7) * 16 + (khat >> 3);          // actual h1 column
        u[j] = (kcol < 120) ? f2bf(w2[n * 120 + kcol]) : (unsigned short)0;
      }
      *(ushort8*)(ws + WS_W2BF + (unsigned)g * 16) = u;
    }
  } else if (blk == 40) {       // G frag image, k-permuted to match h2 packed layout
    for (int e = tid; e < 1024; e += 256) {
      int t = e >> 6, lane = e & 63, q = lane & 15;
      ushort8 u;
#pragma unroll
      for (int j = 0; j < 8; ++j) {
        int khat = t * 32 + (lane >> 4) * 8 + j;           // k-slot in h2 image
        int col = (khat >> 6) * 64 + (khat & 3) * 16 + ((khat >> 2) & 15);
        float v = 0.f;
        if (q < 10) { int kk = q >> 1, c = q & 1; v = ln_g[col] * sms[kk * 1024 + col * 2 + c]; }
        u[j] = f2bf(v);
      }
      *(ushort8*)(ws + WS_GBF + (unsigned)e * 16) = u;
    }
  } else {                      // consts
    float* cst = (float*)(ws + WS_CONST);
    int lane = tid & 63, w = tid >> 6;
    for (int q = w; q < 10; q += 4) {
      int kk = q >> 1, c = q & 1;
      float s = 0.f;
#pragma unroll
      for (int i = 0; i < 8; ++i) { int k = lane + 64 * i; s += ln_b[k] * sms[kk * 1024 + k * 2 + c]; }
#pragma unroll
      for (int o = 32; o >= 1; o >>= 1) s += __shfl_xor(s, o);
      if (lane == 0) cst[q] = s + smb[kk * 2 + c];
    }
    if (tid == 0) cst[16] = tanhf(cs[0]);
    if (tid < 28) cst[32 + tid] = tanhf(embs[tid]);
  }
}

// ---------------------------------------------------------------------------
// K1: h1 = relu(x @ W1^T + b1). 128 rows/block, grid 512 (all-resident, 2/CU).
// Wave = 16-ROW slice: A-frags load DIRECT global->reg (coalesced: 16 rows x
// 128B per frag across the wave), depth-2 register prefetch (~2-step flight
// covers HBM latency, per-wave auto-waits instead of block barriers).
// Only W1 (L2-resident, 16KB/step) is LDS-staged, double-buffered; one
// s_barrier + counted vmcnt(4) per step drains exactly the 2 W gloads.
// Output: k-permuted swizzled bf16 image (ds_write_b128 packs 8 cols).
// ---------------------------------------------------------------------------
__global__ __launch_bounds__(512, 4) void k1_gemm1(
    const float* __restrict__ x, const unsigned char* __restrict__ w1bf,
    const float* __restrict__ b1, unsigned char* __restrict__ h1bf) {
  __shared__ unsigned char lds[32768];    // W dbuf 2x16KB; epilogue: h1 image 32KB
  const int tid = threadIdx.x, lane = tid & 63, w = tid >> 6;
  const int l15 = lane & 15, l4 = lane >> 4;

  // bias first (8 scalar loads; drained by prologue vmcnt(8))
  float b1v[8];
#pragma unroll
  for (int nt = 0; nt < 8; ++nt) {
    int col = nt * 16 + l15;
    b1v[nt] = b1[col < 120 ? col : 119];
  }
  __builtin_amdgcn_sched_barrier(0);

  const float* xbase = x + ((long)blockIdx.x * 128 + w * 16 + l15) * 1024 + l4 * 8;
  const unsigned char* wsrc = w1bf + w * 2048 + lane * 16;

  floatx4 acc[8];
#pragma unroll
  for (int i = 0; i < 8; ++i) acc[i] = floatx4{0.f, 0.f, 0.f, 0.f};

  float4 p[2][4];
  // ---- prologue: W(0) gloads, then x(0)->p[0], x(1)->p[1]
  gload16(wsrc, lds + w * 2048);
  gload16(wsrc + 1024, lds + w * 2048 + 1024);
  __builtin_amdgcn_sched_barrier(0);
#pragma unroll
  for (int ss = 0; ss < 2; ++ss) {
    p[0][ss * 2]     = *(const float4*)(xbase + ss * 32);
    p[0][ss * 2 + 1] = *(const float4*)(xbase + ss * 32 + 4);
  }
#pragma unroll
  for (int ss = 0; ss < 2; ++ss) {
    p[1][ss * 2]     = *(const float4*)(xbase + 64 + ss * 32);
    p[1][ss * 2 + 1] = *(const float4*)(xbase + 64 + ss * 32 + 4);
  }
  __builtin_amdgcn_sched_barrier(0);
  asm volatile("s_waitcnt vmcnt(8)" ::: "memory");   // drain b1v + W(0); x stays in flight
  __builtin_amdgcn_s_barrier();

#pragma unroll
  for (int t = 0; t < 16; ++t) {
    const int cur = t & 1;
    // cvt current x regs (drained by the t-1 barrier's vmcnt) -> A-frags
    short8 afr[2];
#pragma unroll
    for (int ss = 0; ss < 2; ++ss) {
      float4 a0 = p[cur][ss * 2], a1 = p[cur][ss * 2 + 1];
      union { unsigned u[4]; short8 s; } tmp;
      tmp.u[0] = cvtpk(a0.x, a0.y);
      tmp.u[1] = cvtpk(a0.z, a0.w);
      tmp.u[2] = cvtpk(a1.x, a1.y);
      tmp.u[3] = cvtpk(a1.z, a1.w);
      afr[ss] = tmp.s;
    }
    __builtin_amdgcn_sched_barrier(0);
    // W(t+1) gloads (oldest VM ops this step)
    if (t < 15) {
      gload16(wsrc + (t + 1) * 16384, lds + (cur ^ 1) * 16384 + w * 2048);
      gload16(wsrc + (t + 1) * 16384 + 1024, lds + (cur ^ 1) * 16384 + w * 2048 + 1024);
    }
    __builtin_amdgcn_sched_barrier(0);
    // x(t+2) loads into the just-freed reg set (fly across 2 barriers)
    if (t < 14) {
#pragma unroll
      for (int ss = 0; ss < 2; ++ss) {
        p[cur][ss * 2]     = *(const float4*)(xbase + (t + 2) * 64 + ss * 32);
        p[cur][ss * 2 + 1] = *(const float4*)(xbase + (t + 2) * 64 + ss * 32 + 4);
      }
    }
    __builtin_amdgcn_sched_barrier(0);
    // MFMA: 2 ss x 8 nt, B-frags from LDS (shared W tile)
    const unsigned char* Wc = lds + cur * 16384;
#pragma unroll
    for (int ss = 0; ss < 2; ++ss)
#pragma unroll
      for (int nt = 0; nt < 8; ++nt) {
        int n = nt * 16 + l15;
        short8 b = *(const short8*)(Wc + n * 128 + ((ss * 64 + l4 * 16) ^ ((n & 7) << 4)));
        acc[nt] = __builtin_amdgcn_mfma_f32_16x16x32_bf16(afr[ss], b, acc[nt], 0, 0, 0);
      }
    // counted drain: W(t+1) done; x(t+2) stays in flight
    if (t < 14)       asm volatile("s_waitcnt vmcnt(4) lgkmcnt(0)" ::: "memory");
    else if (t == 14) asm volatile("s_waitcnt vmcnt(0) lgkmcnt(0)" ::: "memory");
    else              asm volatile("s_waitcnt lgkmcnt(0)" ::: "memory");
    __builtin_amdgcn_s_barrier();
  }

  // epilogue: bias+relu, pack 8 cols -> k-permuted swizzled image, b128 writes
#pragma unroll
  for (int r = 0; r < 4; ++r) {
    int row = w * 16 + l4 * 4 + r;
    float v[8];
#pragma unroll
    for (int nt = 0; nt < 8; ++nt) {
      float t0 = acc[nt][r] + b1v[nt];
      v[nt] = t0 > 0.f ? t0 : 0.f;
    }
    if (l15 >= 8) v[7] = 0.f;                 // cols 120..127 -> 0
    union { unsigned u[4]; short8 s; } tmp;
    tmp.u[0] = cvtpk(v[0], v[1]);
    tmp.u[1] = cvtpk(v[2], v[3]);
    tmp.u[2] = cvtpk(v[4], v[5]);
    tmp.u[3] = cvtpk(v[6], v[7]);
    *(short8*)(lds + row * 256 + ((l15 * 16) ^ ((row & 7) << 4))) = tmp.s;
  }
  __syncthreads();
  {
    const unsigned char* s = lds + tid * 64;
    unsigned char* d = h1bf + (long)blockIdx.x * 32768 + tid * 64;
    *(float4*)(d)      = *(const float4*)(s);
    *(float4*)(d + 16) = *(const float4*)(s + 16);
    *(float4*)(d + 32) = *(const float4*)(s + 32);
    *(float4*)(d + 48) = *(const float4*)(s + 48);
  }
}

// ---------------------------------------------------------------------------
// K2: fused GEMM2 -> LN -> GEMM3 (heads) -> CE tail. 64 rows/block, 8 waves.
// W2/G consumed as frag-ordered register operands from L2-resident images.
// h2 written as packed ds_write_b64 in k-permuted layout (G image matches).
// LDS 76800B -> 2 blocks/CU.
// ---------------------------------------------------------------------------
__global__ __launch_bounds__(512, 4) void k2_fused(
    const unsigned char* __restrict__ h1bf, const unsigned char* __restrict__ w2f,
    const unsigned char* __restrict__ gbf, const float* __restrict__ cst,
    const float* __restrict__ b2, const int* __restrict__ labels,
    const int* __restrict__ domain, float* __restrict__ out,
    float* __restrict__ partials) {
  extern __shared__ unsigned char lds[];
  unsigned char* h1s = lds;                  // [0,16384)
  unsigned char* h2s = lds;                  // phase B: [0,65536)
  float* stats = (float*)(lds + 65536);      // [64][20]
  float* musig = (float*)(lds + 70656);      // [64][2]
  float* Af    = (float*)(lds + 71168);      // [64][20]

  const int tid = threadIdx.x, lane = tid & 63, w = tid >> 6;
  const int l15 = lane & 15, l4 = lane >> 4;
  const long row0 = (long)blockIdx.x * 64;
  const int n0 = w * 64;

  // ---- stage h1 tile (16 KB): half of k1-block (blockIdx>>1)'s 32KB image
  {
    const unsigned char* hs = h1bf + ((long)(blockIdx.x >> 1)) * 32768 +
                              (blockIdx.x & 1) * 16384 + w * 2048 + lane * 16;
    gload16(hs, h1s + w * 2048);
    gload16(hs + 1024, h1s + w * 2048 + 1024);
  }
  float b2v[4];
#pragma unroll
  for (int nt = 0; nt < 4; ++nt) b2v[nt] = b2[n0 + nt * 16 + l15];
  __syncthreads();

  // ---- GEMM2: 64 rows x 64 cols per wave, K=128 (k-permuted; W2 image matches)
  floatx4 acc[4][4];
#pragma unroll
  for (int i = 0; i < 4; ++i)
#pragma unroll
    for (int j = 0; j < 4; ++j) acc[i][j] = floatx4{0.f, 0.f, 0.f, 0.f};
#pragma unroll
  for (int ks = 0; ks < 4; ++ks) {
    short8 a[4], b[4];
#pragma unroll
    for (int nt = 0; nt < 4; ++nt)
      b[nt] = *(const short8*)(w2f + (((w * 4 + ks) * 4 + nt) * 64 + lane) * 16);
#pragma unroll
    for (int mt = 0; mt < 4; ++mt) {
      int r = mt * 16 + l15;
      a[mt] = *(const short8*)(h1s + r * 256 + ((ks * 64 + l4 * 16) ^ ((r & 7) << 4)));
    }
#pragma unroll
    for (int mt = 0; mt < 4; ++mt)
#pragma unroll
      for (int nt = 0; nt < 4; ++nt)
        acc[mt][nt] = __builtin_amdgcn_mfma_f32_16x16x32_bf16(a[mt], b[nt], acc[mt][nt], 0, 0, 0);
  }

  // ---- bias+relu in regs; LN stats partials (l15-group reduce)
#pragma unroll
  for (int mt = 0; mt < 4; ++mt)
#pragma unroll
    for (int nt = 0; nt < 4; ++nt)
#pragma unroll
      for (int r = 0; r < 4; ++r) {
        float v = acc[mt][nt][r] + b2v[nt];
        acc[mt][nt][r] = v > 0.f ? v : 0.f;
      }
#pragma unroll
  for (int mt = 0; mt < 4; ++mt)
#pragma unroll
    for (int r = 0; r < 4; ++r) {
      float s = 0.f, q2 = 0.f;
#pragma unroll
      for (int nt = 0; nt < 4; ++nt) { float v = acc[mt][nt][r]; s += v; q2 += v * v; }
#pragma unroll
      for (int o = 1; o <= 8; o <<= 1) { s += __shfl_xor(s, o); q2 += __shfl_xor(q2, o); }
      if (l15 == 0) {
        int row = mt * 16 + l4 * 4 + r;
        stats[row * 20 + w * 2] = s;
        stats[row * 20 + w * 2 + 1] = q2;
      }
    }
  __syncthreads();

  if (tid < 64) {
    float S = 0.f, Q = 0.f;
#pragma unroll
    for (int j = 0; j < 8; ++j) { S += stats[tid * 20 + j * 2]; Q += stats[tid * 20 + j * 2 + 1]; }
    float mu = S * (1.f / 512.f);
    float var = Q * (1.f / 512.f) - mu * mu;
    musig[tid * 2] = mu;
    musig[tid * 2 + 1] = rsqrtf(var + 1e-5f);
  }
  __syncthreads();

  // ---- normalized h2 -> packed bf16 (k-permuted, swizzled): 16 x ds_write_b64
#pragma unroll
  for (int mt = 0; mt < 4; ++mt)
#pragma unroll
    for (int r = 0; r < 4; ++r) {
      int row = mt * 16 + l4 * 4 + r;
      float mu = musig[row * 2], rs = musig[row * 2 + 1];
      uint2 qq;
      qq.x = cvtpk((acc[mt][0][r] - mu) * rs, (acc[mt][1][r] - mu) * rs);
      qq.y = cvtpk((acc[mt][2][r] - mu) * rs, (acc[mt][3][r] - mu) * rs);
      *(uint2*)(h2s + row * 1024 + ((w * 128 + l15 * 8) ^ ((row & 7) << 4))) = qq;
    }
  __syncthreads();

  // ---- GEMM3: A[64][10] = h2n @ G^T ; waves 0..3, K=512 (k-permuted G image)
  if (w < 4) {
    floatx4 a3 = floatx4{0.f, 0.f, 0.f, 0.f};
    int row = w * 16 + l15;
#pragma unroll
    for (int t = 0; t < 16; ++t) {
      short8 aa = *(const short8*)(h2s + row * 1024 + ((t * 64 + l4 * 16) ^ ((row & 7) << 4)));
      short8 bb = *(const short8*)(gbf + t * 1024 + lane * 16);
      a3 = __builtin_amdgcn_mfma_f32_16x16x32_bf16(aa, bb, a3, 0, 0, 0);
    }
#pragma unroll
    for (int reg = 0; reg < 4; ++reg) {
      int orow = w * 16 + l4 * 4 + reg;
      if (l15 < 10) Af[orow * 20 + l15] = a3[reg];
    }
  }
  __syncthreads();

  // ---- tail: per-row logits, CE, partial sums (wave 0)
  if (tid < 64) {
    long grow = row0 + tid;
    float pd[10];
#pragma unroll
    for (int q = 0; q < 10; ++q) pd[q] = Af[tid * 20 + q] + cst[q];
    int lab = labels[grow], dm = domain[grow];
    float cw0 = cst[16];
    float ls0 = cw0 * pd[0], ls1 = cw0 * pd[1];
#pragma unroll
    for (int kk = 1; kk < 5; ++kk) {
      float c = cst[32 + dm * 4 + kk - 1];
      ls0 += c * pd[kk * 2];
      ls1 += c * pd[kk * 2 + 1];
    }
    float lc0 = pd[0], lc1 = pd[1];
    *(float2*)(out + 1 + grow * 2) = float2{lc0, lc1};
    float m1 = fmaxf(lc0, lc1), n1 = fminf(lc0, lc1);
    float lse1 = m1 + logf(1.f + expf(n1 - m1));
    float nllc = lse1 - (lab ? lc1 : lc0);
    float m2 = fmaxf(ls0, ls1), n2 = fminf(ls0, ls1);
    float lse2 = m2 + logf(1.f + expf(n2 - m2));
    float nlls = lse2 - (lab ? ls1 : ls0);
    float wl = lab ? 0.9f : 0.1f;
    float wsum = wl, scom = wl * nllc, sspec = wl * nlls;
#pragma unroll
    for (int o = 32; o >= 1; o >>= 1) {
      wsum += __shfl_xor(wsum, o);
      scom += __shfl_xor(scom, o);
      sspec += __shfl_xor(sspec, o);
    }
    if (tid == 0) {
      partials[(long)blockIdx.x * 4] = wsum;
      partials[(long)blockIdx.x * 4 + 1] = scom;
      partials[(long)blockIdx.x * 4 + 2] = sspec;
    }
  }
}

// ---------------------------------------------------------------------------
// K3: deterministic final reduce + orth loss (exact f32) + scalars.
// ---------------------------------------------------------------------------
__global__ __launch_bounds__(256) void k3_finalize(
    const float* __restrict__ partials, const float* __restrict__ sms,
    float* __restrict__ out) {
  __shared__ float wsums[4][3];
  __shared__ float ow[4];
  const int tid = threadIdx.x;
  const int lane = tid & 63, wid = tid >> 6;
  float sw = 0.f, sc = 0.f, ss = 0.f;
  for (int i = tid; i < 1024; i += 256) {
    sw += partials[i * 4];
    sc += partials[i * 4 + 1];
    ss += partials[i * 4 + 2];
  }
#pragma unroll
  for (int o = 32; o >= 1; o >>= 1) {
    sw += __shfl_xor(sw, o);
    sc += __shfl_xor(sc, o);
    ss += __shfl_xor(ss, o);
  }
  if (lane == 0) { wsums[wid][0] = sw; wsums[wid][1] = sc; wsums[wid][2] = ss; }

  float osum = 0.f;
  for (int p = wid; p < 50; p += 4) {
    int c = p / 25, kk = (p / 5) % 5, j = p % 5;
    float acc = 0.f;
#pragma unroll
    for (int hh = 0; hh < 8; ++hh) {
      int h = lane + 64 * hh;
      acc += sms[kk * 1024 + h * 2 + c] * sms[j * 1024 + h * 2 + c];
    }
#pragma unroll
    for (int o = 32; o >= 1; o >>= 1) acc += __shfl_xor(acc, o);
    float d = acc - ((kk == j) ? 1.f : 0.f);
    osum += d * d;
  }
  if (lane == 0) ow[wid] = osum;
  __syncthreads();
  if (tid == 0) {
    float SW = 0.f, SC = 0.f, SS = 0.f, OS = 0.f;
    for (int w = 0; w < 4; ++w) {
      SW += wsums[w][0]; SC += wsums[w][1]; SS += wsums[w][2]; OS += ow[w];
    }
    float orth = OS * (1.f / 50.f);
    float cls = SC / SW;
    float spec = SS / SW;
    out[0] = cls + spec + orth;
    out[131073] = cls;
    out[131074] = spec;
    out[131075] = orth;
  }
}

extern "C" void kernel_launch(void* const* d_in, const int* in_sizes, int n_in,
                              void* d_out, int out_size, void* d_ws, size_t ws_size,
                              hipStream_t stream) {
  const float* x      = (const float*)d_in[0];
  const int* labels   = (const int*)d_in[1];
  const int* domain   = (const int*)d_in[2];
  const float* fc1_w  = (const float*)d_in[3];
  const float* fc1_b  = (const float*)d_in[4];
  const float* fc2_w  = (const float*)d_in[5];
  const float* fc2_b  = (const float*)d_in[6];
  const float* ln_g   = (const float*)d_in[7];
  const float* ln_b   = (const float*)d_in[8];
  const float* sms    = (const float*)d_in[9];
  const float* sm_b   = (const float*)d_in[10];
  const float* embs   = (const float*)d_in[11];
  const float* cs_wt  = (const float*)d_in[12];
  float* out = (float*)d_out;
  unsigned char* ws = (unsigned char*)d_ws;

  (void)hipFuncSetAttribute((const void*)k2_fused,
                            hipFuncAttributeMaxDynamicSharedMemorySize, 76800);

  hipLaunchKernelGGL(k0_prep, dim3(42), dim3(256), 0, stream,
                     fc1_w, fc2_w, ln_g, ln_b, sms, sm_b, embs, cs_wt, ws);
  hipLaunchKernelGGL(k1_gemm1, dim3(BTOT / 128), dim3(512), 0, stream,
                     x, ws + WS_W1BF, fc1_b, ws + WS_H1BF);
  hipLaunchKernelGGL(k2_fused, dim3(BTOT / 64), dim3(512), 76800, stream,
                     ws + WS_H1BF, ws + WS_W2BF, ws + WS_GBF,
                     (const float*)(ws + WS_CONST), fc2_b,
                     labels, domain, out, (float*)(ws + WS_PART));
  hipLaunchKernelGGL(k3_finalize, dim3(1), dim3(256), 0, stream,
                     (const float*)(ws + WS_PART), sms, out);
}